// Round 8
// baseline (602.673 us; speedup 1.0000x reference)
//
#include <hip/hip_runtime.h>
#include <hip/hip_bf16.h>
#include <math.h>

#define B_SZ 4
#define T_LEN 8192
#define C_IN 7
#define NPATCH 1023
#define DIM 512
#define NH 8
#define HD 64
#define NLAYERS 4
#define MLP_HID 2048
#define M_ROWS (B_SZ * NPATCH)   // 4092
#define KEMB 128                 // padded patch length (112 real + 16 zero)
#define LN_EPS 1e-5f

typedef __attribute__((ext_vector_type(8))) short short8;
typedef __attribute__((ext_vector_type(4))) float float4v;

static __device__ __forceinline__ unsigned short f2bf(float f) {
  __hip_bfloat16 h = __float2bfloat16(f);
  return *reinterpret_cast<unsigned short*>(&h);
}

// async global->LDS DMA, 16B per lane (wave-uniform LDS base + lane*16)
static __device__ __forceinline__ void gload_lds16(const void* g, void* l) {
  __builtin_amdgcn_global_load_lds(
      (const __attribute__((address_space(1))) unsigned int*)g,
      (__attribute__((address_space(3))) unsigned int*)l, 16, 0, 0);
}

// ---------------------------------------------------------------------------
// Fused preprocessing mega-kernel (unchanged from R6).
// ---------------------------------------------------------------------------
#define PB0 3072    // wcvt qkv   (nx=48, ny=16, L=4)
#define PB1 4096    // wcvt proj  (nx=16, ny=16)
#define PB2 8192    // wcvt mlp1  (nx=64, ny=16)
#define PB3 12288   // wcvt mlp2  (nx=16, ny=64)
#define PB4 14334   // patch (2046 blocks)
#define PB5 14590   // wemb (256 blocks)
#define PB6 14718   // rope (128 blocks)

__global__ __launch_bounds__(256) void prep_kernel(
    const float* __restrict__ W_qkv, unsigned short* __restrict__ wqkv_t,
    const float* __restrict__ W_proj, unsigned short* __restrict__ wproj_t,
    const float* __restrict__ W_mlp1, unsigned short* __restrict__ wmlp1_t,
    const float* __restrict__ W_mlp2, unsigned short* __restrict__ wmlp2_t,
    const float* __restrict__ x, unsigned short* __restrict__ Pm,
    const float* __restrict__ W_emb, unsigned short* __restrict__ Wembt,
    float2* __restrict__ rtab) {
  __shared__ float tile[32][33];
  const int bid = blockIdx.x, tid = threadIdx.x;

  auto do_wcvt = [&](const float* W, unsigned short* Wt, int K, int N,
                     int t, int nx, int ny) {
    int xb = t % nx, yb = (t / nx) % ny, L = t / (nx * ny);
    int n0 = xb * 32, k0 = yb * 32;
    const float* Ws = W + (size_t)L * K * N;
    unsigned short* Wd = Wt + (size_t)L * K * N;
    int tx = tid & 31, ty = tid >> 5;
    #pragma unroll
    for (int i = 0; i < 4; ++i)
      tile[ty + i * 8][tx] = Ws[(size_t)(k0 + ty + i * 8) * N + n0 + tx];
    __syncthreads();
    #pragma unroll
    for (int i = 0; i < 4; ++i)
      Wd[(size_t)(n0 + ty + i * 8) * K + k0 + tx] = f2bf(tile[tx][ty + i * 8]);
  };

  if (bid < PB0) {
    do_wcvt(W_qkv, wqkv_t, DIM, 3 * DIM, bid, 48, 16);
  } else if (bid < PB1) {
    do_wcvt(W_proj, wproj_t, DIM, DIM, bid - PB0, 16, 16);
  } else if (bid < PB2) {
    do_wcvt(W_mlp1, wmlp1_t, DIM, MLP_HID, bid - PB1, 64, 16);
  } else if (bid < PB3) {
    do_wcvt(W_mlp2, wmlp2_t, MLP_HID, DIM, bid - PB2, 16, 64);
  } else if (bid < PB4) {
    int idx = (bid - PB3) * 256 + tid;
    if (idx < M_ROWS * KEMB) {
      int row = idx >> 7, c = idx & 127;
      float v = 0.f;
      if (c < 112) {
        int b = row / NPATCH, i = row - b * NPATCH;
        int ci = c >> 4, p = c & 15;
        v = x[((size_t)b * T_LEN + (size_t)i * 8 + p) * C_IN + ci];
      }
      Pm[idx] = f2bf(v);
    }
  } else if (bid < PB5) {
    int idx = (bid - PB4) * 256 + tid;
    if (idx < DIM * KEMB) {
      int n = idx >> 7, k = idx & 127;
      float v = (k < 112) ? W_emb[(size_t)k * DIM + n] : 0.f;
      Wembt[idx] = f2bf(v);
    }
  } else {
    int idx = (bid - PB5) * 256 + tid;
    if (idx < NPATCH * 32) {
      int i = idx >> 5, j = idx & 31;
      float inv = powf(10000.0f, -(float)j * (1.0f / 32.0f));
      float sn, cs;
      sincosf((float)i * inv, &sn, &cs);
      rtab[idx] = make_float2(cs, sn);
    }
  }
}

// ---------------------------------------------------------------------------
// LayerNorm, 4 rows/block. BF: bf16 vs fp32 out.
// ---------------------------------------------------------------------------
template <bool BF>
__global__ __launch_bounds__(256) void ln_kernel(
    const float* __restrict__ in, const float* __restrict__ g,
    const float* __restrict__ bb, void* __restrict__ outv, int M) {
  int row = blockIdx.x * 4 + (threadIdx.x >> 6);
  if (row >= M) return;
  int lane = threadIdx.x & 63;
  const float* xr = in + (size_t)row * DIM;
  float v[8];
  float s = 0.f;
  #pragma unroll
  for (int k = 0; k < 8; ++k) { v[k] = xr[lane + 64 * k]; s += v[k]; }
  #pragma unroll
  for (int off = 32; off; off >>= 1) s += __shfl_down(s, off);
  s = __shfl(s, 0);
  float mu = s * (1.f / DIM);
  float q = 0.f;
  #pragma unroll
  for (int k = 0; k < 8; ++k) { float d = v[k] - mu; q = fmaf(d, d, q); }
  #pragma unroll
  for (int off = 32; off; off >>= 1) q += __shfl_down(q, off);
  q = __shfl(q, 0);
  float rstd = rsqrtf(q * (1.f / DIM) + LN_EPS);
  #pragma unroll
  for (int k = 0; k < 8; ++k) {
    int d = lane + 64 * k;
    float r = (v[k] - mu) * rstd * g[d] + bb[d];
    if (BF)
      ((unsigned short*)outv)[(size_t)row * DIM + d] = f2bf(r);
    else
      ((float*)outv)[(size_t)row * DIM + d] = r;
  }
}

// ---------------------------------------------------------------------------
// bf16 MFMA GEMM v5: DMA staging, XCD swizzle, 3-buffer LDS with COUNTED
// vmcnt + raw s_barrier (T3/T4 2-deep pipeline).
//  Per iter t:
//    s_waitcnt lgkmcnt(0)   : own ds_reads of iter t-1 done (WAR safety for
//                             buf (t+2)%3, which stage() overwrites below)
//    s_waitcnt vmcnt(CPW|0) : own tile-t DMA instrs retired. Outstanding at
//                             this point = tiles {t, t+1} = 2*CPW per wave;
//                             vmcnt(CPW) retires exactly tile t. Last iter
//                             (no t+1) uses vmcnt(0).
//    s_barrier              : tile t visible to all; prev readers done
//    stage((t+2)%3)         : DMA flies across TWO MFMA phases
//    ds_read + MFMA buf t%3
//  No other vmem ops exist inside the loop (bias/rtab reads are epilogue).
//  LDS: 64x64 BK64 = 48 KB; 64x128 BK64 = 72 KB (2 blk/CU at 144 KB);
//  128x128 BK32 = 48 KB.
// EPI: 1 = bias+res -> fp32; 2 = bias+GELU -> bf16; 3 = bias -> bf16;
//      5 = bias -> fp32 to Cf and Cf2 (embed); 6 = bias+RoPE -> bf16 (WN=64,
//          q scaled by 0.125*log2e for exp2 softmax downstream).
// ---------------------------------------------------------------------------
template <int TM, int TN, int KSTEP, int EPI>
__global__ __launch_bounds__(256) void mfma_gemm(
    const unsigned short* __restrict__ A, const unsigned short* __restrict__ Bt,
    const float* __restrict__ bias, const float* __restrict__ res,
    float* __restrict__ Cf, float* __restrict__ Cf2,
    unsigned short* __restrict__ Cb, const float2* __restrict__ rtab,
    int M, int N, int K) {
  constexpr int WM = TM / 2, WN = TN / 2;
  constexpr int NI = WM / 16, NJ = WN / 16;
  constexpr int RCH = KSTEP / 8;            // 16B chunks per row (4 or 8)
  constexpr int RPU = 64 / RCH;             // rows per 1KB DMA unit (16 or 8)
  constexpr int AU = TM / RPU;              // A units
  constexpr int NU = (TM + TN) / RPU;       // total units
  constexpr int CPW = NU / 4;               // units (vmcnt instrs) per wave
  constexpr int SH = (KSTEP == 32) ? 1 : 0; // row swizzle shift
  __shared__ __align__(16) unsigned short As[3][TM][KSTEP];
  __shared__ __align__(16) unsigned short Bs[3][TN][KSTEP];
  // XCD-aware decode (nwg % 8 == 0 guaranteed by launch config)
  const int nwg = gridDim.x;
  const int nx = N / TN;
  const int wg = (blockIdx.x & 7) * (nwg >> 3) + (blockIdx.x >> 3);
  const int bm = (wg / nx) * TM;
  const int bn = (wg % nx) * TN;
  const int tid = threadIdx.x;
  const int lane = tid & 63, wave = tid >> 6;
  const int quad = lane >> 4, l16 = lane & 15;
  const int wm = (wave & 1) * WM;
  const int wn = (wave >> 1) * WN;
  const int lrow = lane / RCH, lc = lane & (RCH - 1);   // DMA src decomp
  const int rsw = (l16 >> SH) & (RCH - 1);              // read swizzle

  float4v acc[NI][NJ];
  #pragma unroll
  for (int i = 0; i < NI; ++i)
    #pragma unroll
    for (int j = 0; j < NJ; ++j)
      acc[i][j] = (float4v){0.f, 0.f, 0.f, 0.f};

  auto stage = [&](int bufI, int kk) {
    #pragma unroll
    for (int it = 0; it < CPW; ++it) {
      int u = wave * CPW + it;
      if (u < AU) {
        int row = u * RPU + lrow;
        int col16 = lc ^ ((row >> SH) & (RCH - 1));
        gload_lds16(A + (size_t)(bm + row) * K + kk + col16 * 8,
                    &As[bufI][u * RPU][0]);
      } else {
        int row = (u - AU) * RPU + lrow;
        int col16 = lc ^ ((row >> SH) & (RCH - 1));
        gload_lds16(Bt + (size_t)(bn + row) * K + kk + col16 * 8,
                    &Bs[bufI][(u - AU) * RPU][0]);
      }
    }
  };

  const int NT = K / KSTEP;
  stage(0, 0);
  if (NT > 1) stage(1, KSTEP);
  int bc = 0;
  for (int t = 0; t < NT; ++t) {
    asm volatile("s_waitcnt lgkmcnt(0)" ::: "memory");
    if (t + 1 < NT) {
      asm volatile("s_waitcnt vmcnt(%0)" :: "i"(CPW) : "memory");
    } else {
      asm volatile("s_waitcnt vmcnt(0)" ::: "memory");
    }
    __builtin_amdgcn_s_barrier();
    if (t + 2 < NT) {
      int bs = bc + 2; if (bs >= 3) bs -= 3;
      stage(bs, (t + 2) * KSTEP);
    }
    #pragma unroll
    for (int tt = 0; tt < KSTEP / 32; ++tt) {
      short8 af[NI], bfr[NJ];
      int rslot = (tt * 4 + quad) ^ rsw;
      #pragma unroll
      for (int i = 0; i < NI; ++i)
        af[i] = *(const short8*)&As[bc][wm + i * 16 + l16][rslot * 8];
      #pragma unroll
      for (int j = 0; j < NJ; ++j)
        bfr[j] = *(const short8*)&Bs[bc][wn + j * 16 + l16][rslot * 8];
      __builtin_amdgcn_s_setprio(1);
      #pragma unroll
      for (int i = 0; i < NI; ++i)
        #pragma unroll
        for (int j = 0; j < NJ; ++j)
          acc[i][j] = __builtin_amdgcn_mfma_f32_16x16x32_bf16(
              af[i], bfr[j], acc[i][j], 0, 0, 0);
      __builtin_amdgcn_s_setprio(0);
    }
    bc = (bc == 2) ? 0 : bc + 1;
  }

  if (EPI == 6) {
    const int sec = (bn + wn) >> 9;   // 0=q, 1=k, 2=v (wave-uniform; WN=64)
    #pragma unroll
    for (int i = 0; i < NI; ++i) {
      int gm0 = bm + wm + i * 16 + quad * 4;
      #pragma unroll
      for (int r = 0; r < 4; ++r) {
        int gm = gm0 + r;
        if (gm >= M) continue;
        size_t rowoff = (size_t)gm * N;
        if (sec < 2) {
          int ip = gm; if (ip >= 2046) ip -= 2046; if (ip >= 1023) ip -= 1023;
          // q pre-scaled by log2e so attn can use exp2 directly
          float sc = (sec == 0) ? 0.125f * 1.44269504f : 1.f;
          #pragma unroll
          for (int j = 0; j < NJ / 2; ++j) {
            int gn = bn + wn + j * 16 + l16;
            float v0 = acc[i][j][r] + bias[gn];
            float v1 = acc[i][j + NJ / 2][r] + bias[gn + 32];
            float2 t = rtab[ip * 32 + j * 16 + l16];
            Cb[rowoff + gn]      = f2bf((v0 * t.x - v1 * t.y) * sc);
            Cb[rowoff + gn + 32] = f2bf((v1 * t.x + v0 * t.y) * sc);
          }
        } else {
          #pragma unroll
          for (int j = 0; j < NJ; ++j) {
            int gn = bn + wn + j * 16 + l16;
            Cb[rowoff + gn] = f2bf(acc[i][j][r] + bias[gn]);
          }
        }
      }
    }
    return;
  }

  #pragma unroll
  for (int j = 0; j < NJ; ++j) {
    int gn = bn + wn + j * 16 + l16;
    float bv = bias[gn];
    #pragma unroll
    for (int i = 0; i < NI; ++i) {
      int gm0 = bm + wm + i * 16 + quad * 4;
      #pragma unroll
      for (int r = 0; r < 4; ++r) {
        int gm = gm0 + r;
        if (gm < M) {
          float v = acc[i][j][r] + bv;
          size_t off = (size_t)gm * N + gn;
          if (EPI == 1) {
            Cf[off] = v + res[off];
          } else if (EPI == 2) {
            Cb[off] = f2bf(0.5f * v * (1.f + erff(v * 0.70710678118f)));
          } else if (EPI == 3) {
            Cb[off] = f2bf(v);
          } else {
            Cf[off] = v;
            Cf2[off] = v;
          }
        }
      }
    }
  }
}

// ---------------------------------------------------------------------------
// MFMA flash attention v5.1 (unchanged from R7): in-block split-K, 8 waves,
// exp2 softmax.
// ---------------------------------------------------------------------------
#define APITCH 72

__global__ __launch_bounds__(512, 4) void attn_kernel(
    const unsigned short* __restrict__ qkvb, unsigned short* __restrict__ o) {
  const int bid = blockIdx.x;
  const int xcd = bid & 7, slot = bid >> 3;
  const int qt0 = (slot & 15) * 64;
  const int gh = xcd + 8 * (slot >> 4);    // 0..31
  const int h = gh & 7, b = gh >> 3;

  const int tid = threadIdx.x;
  const int lane = tid & 63, wave = tid >> 6;
  const int quad = lane >> 4, l16 = lane & 15;
  const int half = wave >> 2, wq = wave & 3;

  __shared__ __align__(16) unsigned short Ks[2][64][APITCH];  // [half][key][d]
  __shared__ __align__(16) unsigned short Vt[2][64][APITCH];  // [half][d][key]
  __shared__ __align__(16) unsigned short Ps[8][16][APITCH];  // per-wave P; merge buf

  short8 aq0 = {0, 0, 0, 0, 0, 0, 0, 0}, aq1 = aq0;
  {
    int qrow = qt0 + wq * 16 + l16;
    if (qrow < NPATCH) {
      const uint4* qr = (const uint4*)(qkvb + (size_t)(b * NPATCH + qrow) * (3 * DIM) + h * HD + quad * 8);
      aq0 = __builtin_bit_cast(short8, qr[0]);
      aq1 = __builtin_bit_cast(short8, qr[4]);
    }
  }

  const int krow = tid >> 2, kc0 = (tid & 3) * 16;
  const int kp2 = tid & 63, dg = tid >> 6;
  uint4 pk0, pk1, pv0, pv1;
  auto load_kv = [&](int js) {
    pk0 = pk1 = pv0 = pv1 = make_uint4(0u, 0u, 0u, 0u);
    int jk = js + krow;
    if (jk < NPATCH) {
      const unsigned short* kb = qkvb + (size_t)(b * NPATCH + jk) * (3 * DIM) + DIM + h * HD;
      pk0 = *(const uint4*)(kb + kc0);
      pk1 = *(const uint4*)(kb + kc0 + 8);
    }
    int jv = js + 2 * kp2;
    const unsigned short* vb = qkvb + (size_t)(b * NPATCH + jv) * (3 * DIM) + 2 * DIM + h * HD + dg * 8;
    if (jv < NPATCH)     pv0 = *(const uint4*)vb;
    if (jv + 1 < NPATCH) pv1 = *(const uint4*)(vb + 3 * DIM);
  };

  load_kv(0);

  float4v accO[4];
  #pragma unroll
  for (int j2 = 0; j2 < 4; ++j2) accO[j2] = (float4v){0.f, 0.f, 0.f, 0.f};
  float m_run[4] = {-1e30f, -1e30f, -1e30f, -1e30f};
  float lp[4] = {0.f, 0.f, 0.f, 0.f};

  constexpr int NIT = (NPATCH + 127) / 128;   // 8 slabs of 128 keys
  for (int it = 0; it < NIT; ++it) {
    if (it > 0) __syncthreads();
    {
      *(uint4*)&Ks[krow >> 6][krow & 63][kc0] = pk0;
      *(uint4*)&Ks[krow >> 6][krow & 63][kc0 + 8] = pk1;
      unsigned short va[8], vb8[8];
      *(uint4*)&va[0] = pv0;
      *(uint4*)&vb8[0] = pv1;
      const int vh = kp2 >> 5, lp2 = kp2 & 31;
      #pragma unroll
      for (int u = 0; u < 8; ++u) {
        unsigned pk = (unsigned)va[u] | ((unsigned)vb8[u] << 16);
        *(unsigned*)&Vt[vh][dg * 8 + u][2 * lp2] = pk;
      }
    }
    __syncthreads();
    if (it + 1 < NIT) load_kv((it + 1) * 128);

    const int j0 = it * 128 + half * 64;

    float4v s[4];
    __builtin_amdgcn_s_setprio(1);
    #pragma unroll
    for (int j = 0; j < 4; ++j) {
      s[j] = (float4v){0.f, 0.f, 0.f, 0.f};
      short8 bk0 = *(const short8*)&Ks[half][j * 16 + l16][quad * 8];
      short8 bk1 = *(const short8*)&Ks[half][j * 16 + l16][32 + quad * 8];
      s[j] = __builtin_amdgcn_mfma_f32_16x16x32_bf16(aq0, bk0, s[j], 0, 0, 0);
      s[j] = __builtin_amdgcn_mfma_f32_16x16x32_bf16(aq1, bk1, s[j], 0, 0, 0);
    }
    __builtin_amdgcn_s_setprio(0);

    // online softmax in exp2 units (s already scaled by log2e)
    float mx[4];
    #pragma unroll
    for (int r = 0; r < 4; ++r)
      mx[r] = fmaxf(fmaxf(s[0][r], s[1][r]), fmaxf(s[2][r], s[3][r]));
    #pragma unroll
    for (int mask = 1; mask < 16; mask <<= 1)
      #pragma unroll
      for (int r = 0; r < 4; ++r)
        mx[r] = fmaxf(mx[r], __shfl_xor(mx[r], mask));
    float gmax = fmaxf(fmaxf(mx[0] - m_run[0], mx[1] - m_run[1]),
                       fmaxf(mx[2] - m_run[2], mx[3] - m_run[3]));
    if (!__all(gmax <= 11.0f)) {   // defer-max: 11 bits ~ 7.6 nats
      #pragma unroll
      for (int r = 0; r < 4; ++r) {
        float mnew = fmaxf(m_run[r], mx[r]);
        float al = exp2f(m_run[r] - mnew);
        m_run[r] = mnew;
        lp[r] *= al;
        #pragma unroll
        for (int j2 = 0; j2 < 4; ++j2) accO[j2][r] *= al;
      }
    }
    #pragma unroll
    for (int j = 0; j < 4; ++j) {
      bool valid = (j0 + j * 16 + l16) < NPATCH;
      #pragma unroll
      for (int r = 0; r < 4; ++r) {
        float p = valid ? exp2f(s[j][r] - m_run[r]) : 0.f;
        lp[r] += p;
        Ps[wave][quad * 4 + r][j * 16 + l16] = f2bf(p);
      }
    }

    short8 pa0 = *(const short8*)&Ps[wave][l16][quad * 8];
    short8 pa1 = *(const short8*)&Ps[wave][l16][32 + quad * 8];
    __builtin_amdgcn_s_setprio(1);
    #pragma unroll
    for (int j2 = 0; j2 < 4; ++j2) {
      short8 v0 = *(const short8*)&Vt[half][j2 * 16 + l16][quad * 8];
      short8 v1 = *(const short8*)&Vt[half][j2 * 16 + l16][32 + quad * 8];
      accO[j2] = __builtin_amdgcn_mfma_f32_16x16x32_bf16(pa0, v0, accO[j2], 0, 0, 0);
      accO[j2] = __builtin_amdgcn_mfma_f32_16x16x32_bf16(pa1, v1, accO[j2], 0, 0, 0);
    }
    __builtin_amdgcn_s_setprio(0);
  }

  #pragma unroll
  for (int mask = 1; mask < 16; mask <<= 1)
    #pragma unroll
    for (int r = 0; r < 4; ++r)
      lp[r] += __shfl_xor(lp[r], mask);

  float* Pf = (float*)&Ps[0][0][0];
  __syncthreads();
  if (half == 1) {
    #pragma unroll
    for (int j2 = 0; j2 < 4; ++j2)
      #pragma unroll
      for (int r = 0; r < 4; ++r)
        Pf[((wq * 64 + lane) << 4) + j2 * 4 + r] = accO[j2][r];
    if (l16 == 0) {
      #pragma unroll
      for (int r = 0; r < 4; ++r) {
        Pf[4096 + ((wq * 16 + quad * 4 + r) << 1)]     = m_run[r];
        Pf[4096 + ((wq * 16 + quad * 4 + r) << 1) + 1] = lp[r];
      }
    }
  }
  __syncthreads();
  if (half == 0) {
    #pragma unroll
    for (int r = 0; r < 4; ++r) {
      float m1 = Pf[4096 + ((wq * 16 + quad * 4 + r) << 1)];
      float l1 = Pf[4096 + ((wq * 16 + quad * 4 + r) << 1) + 1];
      float M = fmaxf(m_run[r], m1);
      float w0 = exp2f(m_run[r] - M), w1 = exp2f(m1 - M);
      float inv = 1.f / (w0 * lp[r] + w1 * l1);
      int qi = qt0 + wq * 16 + quad * 4 + r;
      if (qi < NPATCH) {
        size_t off = (size_t)(b * NPATCH + qi) * DIM + h * HD + l16;
        #pragma unroll
        for (int j2 = 0; j2 < 4; ++j2) {
          float a1 = Pf[((wq * 64 + lane) << 4) + j2 * 4 + r];
          o[off + j2 * 16] = f2bf((w0 * accO[j2][r] + w1 * a1) * inv);
        }
      }
    }
  }
}

// ---------------------------------------------------------------------------
extern "C" void kernel_launch(void* const* d_in, const int* in_sizes, int n_in,
                              void* d_out, int out_size, void* d_ws, size_t ws_size,
                              hipStream_t stream) {
  const float* x      = (const float*)d_in[0];
  const float* W_emb  = (const float*)d_in[1];
  const float* b_emb  = (const float*)d_in[2];
  const float* ln1_g  = (const float*)d_in[3];
  const float* ln1_b  = (const float*)d_in[4];
  const float* W_qkv  = (const float*)d_in[5];
  const float* b_qkv  = (const float*)d_in[6];
  const float* W_proj = (const float*)d_in[7];
  const float* b_proj = (const float*)d_in[8];
  const float* ln2_g  = (const float*)d_in[9];
  const float* ln2_b  = (const float*)d_in[10];
  const float* W_mlp1 = (const float*)d_in[11];
  const float* b_mlp1 = (const float*)d_in[12];
  const float* W_mlp2 = (const float*)d_in[13];
  const float* b_mlp2 = (const float*)d_in[14];
  const float* lnf_g  = (const float*)d_in[15];
  const float* lnf_b  = (const float*)d_in[16];
  float* out = (float*)d_out;

  float* h              = (float*)d_ws;
  unsigned short* qkvb  = (unsigned short*)(h + (size_t)M_ROWS * DIM);
  unsigned short* midbf = qkvb;   // alias: qkvb dead after attn
  unsigned short* ybf   = qkvb + (size_t)M_ROWS * MLP_HID;
  unsigned short* obf   = ybf;    // alias: ybf dead after its GEMM
  unsigned short* wqkv_t  = ybf + (size_t)M_ROWS * DIM;
  unsigned short* wproj_t = wqkv_t  + (size_t)NLAYERS * DIM * 3 * DIM;
  unsigned short* wmlp1_t = wproj_t + (size_t)NLAYERS * DIM * DIM;
  unsigned short* wmlp2_t = wmlp1_t + (size_t)NLAYERS * DIM * MLP_HID;
  float2* rtab = (float2*)(wmlp2_t + (size_t)NLAYERS * MLP_HID * DIM);
  unsigned short* Pm    = (unsigned short*)(rtab + (size_t)NPATCH * 32);
  unsigned short* Wembt = Pm + (size_t)M_ROWS * KEMB;

  prep_kernel<<<dim3(PB6), 256, 0, stream>>>(
      W_qkv, wqkv_t, W_proj, wproj_t, W_mlp1, wmlp1_t, W_mlp2, wmlp2_t,
      x, Pm, W_emb, Wembt, rtab);

  const int LNG = (M_ROWS + 3) / 4;        // 1023
  // 1-D swizzled grids: nwg = (N/TN) * ceil(M/TM), all divisible by 8
  const int G64x64  = (DIM / 64) * 64;         // 512
  const int Gqkv    = (3 * DIM / 128) * 64;    // 768
  const int Gmlp1   = (MLP_HID / 128) * 32;    // 512

  // embed: out & h = Pm @ Wembt^T + b_emb  (64x64, BK=64)
  mfma_gemm<64, 64, 64, 5><<<dim3(G64x64), 256, 0, stream>>>(
      Pm, Wembt, b_emb, nullptr, out, h, nullptr, nullptr, M_ROWS, DIM, KEMB);

  for (int L = 0; L < NLAYERS; ++L) {
    ln_kernel<true><<<LNG, 256, 0, stream>>>(h, ln1_g + L * DIM, ln1_b + L * DIM, ybf, M_ROWS);
    // qkv with fused RoPE (64x128, BK=64)
    mfma_gemm<64, 128, 64, 6><<<dim3(Gqkv), 256, 0, stream>>>(
        ybf, wqkv_t + (size_t)L * DIM * 3 * DIM, b_qkv + L * 3 * DIM,
        nullptr, nullptr, nullptr, qkvb, rtab, M_ROWS, 3 * DIM, DIM);
    attn_kernel<<<dim3(512), 512, 0, stream>>>(qkvb, obf);
    // proj: h += o @ Wp + bias  (64x64, BK=64)
    mfma_gemm<64, 64, 64, 1><<<dim3(G64x64), 256, 0, stream>>>(
        obf, wproj_t + (size_t)L * DIM * DIM, b_proj + L * DIM,
        h, h, nullptr, nullptr, nullptr, M_ROWS, DIM, DIM);
    ln_kernel<true><<<LNG, 256, 0, stream>>>(h, ln2_g + L * DIM, ln2_b + L * DIM, ybf, M_ROWS);
    // mlp1 + GELU (128x128, BK=32)
    mfma_gemm<128, 128, 32, 2><<<dim3(Gmlp1), 256, 0, stream>>>(
        ybf, wmlp1_t + (size_t)L * DIM * MLP_HID, b_mlp1 + L * MLP_HID,
        nullptr, nullptr, nullptr, midbf, nullptr, M_ROWS, MLP_HID, DIM);
    // mlp2: h += mid @ Wm2 + bias  (64x64, BK=64)
    mfma_gemm<64, 64, 64, 1><<<dim3(G64x64), 256, 0, stream>>>(
        midbf, wmlp2_t + (size_t)L * MLP_HID * DIM, b_mlp2 + L * DIM,
        h, h, nullptr, nullptr, nullptr, M_ROWS, DIM, MLP_HID);
  }

  ln_kernel<false><<<LNG, 256, 0, stream>>>(h, lnf_g, lnf_b, out + (size_t)M_ROWS * DIM, M_ROWS);
}

// Round 9
// 589.502 us; speedup vs baseline: 1.0223x; 1.0223x over previous
//
#include <hip/hip_runtime.h>
#include <hip/hip_bf16.h>
#include <math.h>

#define B_SZ 4
#define T_LEN 8192
#define C_IN 7
#define NPATCH 1023
#define DIM 512
#define NH 8
#define HD 64
#define NLAYERS 4
#define MLP_HID 2048
#define M_ROWS (B_SZ * NPATCH)   // 4092
#define KEMB 128                 // padded patch length (112 real + 16 zero)
#define LN_EPS 1e-5f

typedef __attribute__((ext_vector_type(8))) short short8;
typedef __attribute__((ext_vector_type(4))) float float4v;

static __device__ __forceinline__ unsigned short f2bf(float f) {
  __hip_bfloat16 h = __float2bfloat16(f);
  return *reinterpret_cast<unsigned short*>(&h);
}

// async global->LDS DMA, 16B per lane (wave-uniform LDS base + lane*16)
static __device__ __forceinline__ void gload_lds16(const void* g, void* l) {
  __builtin_amdgcn_global_load_lds(
      (const __attribute__((address_space(1))) unsigned int*)g,
      (__attribute__((address_space(3))) unsigned int*)l, 16, 0, 0);
}

// ---------------------------------------------------------------------------
// Fused preprocessing mega-kernel (unchanged from R6).
// ---------------------------------------------------------------------------
#define PB0 3072    // wcvt qkv   (nx=48, ny=16, L=4)
#define PB1 4096    // wcvt proj  (nx=16, ny=16)
#define PB2 8192    // wcvt mlp1  (nx=64, ny=16)
#define PB3 12288   // wcvt mlp2  (nx=16, ny=64)
#define PB4 14334   // patch (2046 blocks)
#define PB5 14590   // wemb (256 blocks)
#define PB6 14718   // rope (128 blocks)

__global__ __launch_bounds__(256) void prep_kernel(
    const float* __restrict__ W_qkv, unsigned short* __restrict__ wqkv_t,
    const float* __restrict__ W_proj, unsigned short* __restrict__ wproj_t,
    const float* __restrict__ W_mlp1, unsigned short* __restrict__ wmlp1_t,
    const float* __restrict__ W_mlp2, unsigned short* __restrict__ wmlp2_t,
    const float* __restrict__ x, unsigned short* __restrict__ Pm,
    const float* __restrict__ W_emb, unsigned short* __restrict__ Wembt,
    float2* __restrict__ rtab) {
  __shared__ float tile[32][33];
  const int bid = blockIdx.x, tid = threadIdx.x;

  auto do_wcvt = [&](const float* W, unsigned short* Wt, int K, int N,
                     int t, int nx, int ny) {
    int xb = t % nx, yb = (t / nx) % ny, L = t / (nx * ny);
    int n0 = xb * 32, k0 = yb * 32;
    const float* Ws = W + (size_t)L * K * N;
    unsigned short* Wd = Wt + (size_t)L * K * N;
    int tx = tid & 31, ty = tid >> 5;
    #pragma unroll
    for (int i = 0; i < 4; ++i)
      tile[ty + i * 8][tx] = Ws[(size_t)(k0 + ty + i * 8) * N + n0 + tx];
    __syncthreads();
    #pragma unroll
    for (int i = 0; i < 4; ++i)
      Wd[(size_t)(n0 + ty + i * 8) * K + k0 + tx] = f2bf(tile[tx][ty + i * 8]);
  };

  if (bid < PB0) {
    do_wcvt(W_qkv, wqkv_t, DIM, 3 * DIM, bid, 48, 16);
  } else if (bid < PB1) {
    do_wcvt(W_proj, wproj_t, DIM, DIM, bid - PB0, 16, 16);
  } else if (bid < PB2) {
    do_wcvt(W_mlp1, wmlp1_t, DIM, MLP_HID, bid - PB1, 64, 16);
  } else if (bid < PB3) {
    do_wcvt(W_mlp2, wmlp2_t, MLP_HID, DIM, bid - PB2, 16, 64);
  } else if (bid < PB4) {
    int idx = (bid - PB3) * 256 + tid;
    if (idx < M_ROWS * KEMB) {
      int row = idx >> 7, c = idx & 127;
      float v = 0.f;
      if (c < 112) {
        int b = row / NPATCH, i = row - b * NPATCH;
        int ci = c >> 4, p = c & 15;
        v = x[((size_t)b * T_LEN + (size_t)i * 8 + p) * C_IN + ci];
      }
      Pm[idx] = f2bf(v);
    }
  } else if (bid < PB5) {
    int idx = (bid - PB4) * 256 + tid;
    if (idx < DIM * KEMB) {
      int n = idx >> 7, k = idx & 127;
      float v = (k < 112) ? W_emb[(size_t)k * DIM + n] : 0.f;
      Wembt[idx] = f2bf(v);
    }
  } else {
    int idx = (bid - PB5) * 256 + tid;
    if (idx < NPATCH * 32) {
      int i = idx >> 5, j = idx & 31;
      float inv = powf(10000.0f, -(float)j * (1.0f / 32.0f));
      float sn, cs;
      sincosf((float)i * inv, &sn, &cs);
      rtab[idx] = make_float2(cs, sn);
    }
  }
}

// ---------------------------------------------------------------------------
// LayerNorm, 4 rows/block, float4-vectorized (G13): 2x 16B loads per row
// per lane, packed 8B bf16 stores. BF: bf16 vs fp32 out.
// ---------------------------------------------------------------------------
template <bool BF>
__global__ __launch_bounds__(256) void ln_kernel(
    const float* __restrict__ in, const float* __restrict__ g,
    const float* __restrict__ bb, void* __restrict__ outv, int M) {
  int row = blockIdx.x * 4 + (threadIdx.x >> 6);
  if (row >= M) return;
  int lane = threadIdx.x & 63;
  const float4* xr = (const float4*)(in + (size_t)row * DIM) + lane;
  float4 v0 = xr[0];     // cols lane*4   .. +3
  float4 v1 = xr[64];    // cols 256+lane*4 .. +3
  float s = (v0.x + v0.y) + (v0.z + v0.w) + (v1.x + v1.y) + (v1.z + v1.w);
  #pragma unroll
  for (int off = 32; off; off >>= 1) s += __shfl_down(s, off);
  s = __shfl(s, 0);
  float mu = s * (1.f / DIM);
  float dx0 = v0.x - mu, dy0 = v0.y - mu, dz0 = v0.z - mu, dw0 = v0.w - mu;
  float dx1 = v1.x - mu, dy1 = v1.y - mu, dz1 = v1.z - mu, dw1 = v1.w - mu;
  float q = dx0 * dx0 + dy0 * dy0 + dz0 * dz0 + dw0 * dw0
          + dx1 * dx1 + dy1 * dy1 + dz1 * dz1 + dw1 * dw1;
  #pragma unroll
  for (int off = 32; off; off >>= 1) q += __shfl_down(q, off);
  q = __shfl(q, 0);
  float rstd = rsqrtf(q * (1.f / DIM) + LN_EPS);
  const float4* g4 = (const float4*)g + lane;
  const float4* b4 = (const float4*)bb + lane;
  float4 ga = g4[0], gb = g4[64], ba = b4[0], bc = b4[64];
  float r0 = dx0 * rstd * ga.x + ba.x, r1 = dy0 * rstd * ga.y + ba.y;
  float r2 = dz0 * rstd * ga.z + ba.z, r3 = dw0 * rstd * ga.w + ba.w;
  float r4 = dx1 * rstd * gb.x + bc.x, r5 = dy1 * rstd * gb.y + bc.y;
  float r6 = dz1 * rstd * gb.z + bc.z, r7 = dw1 * rstd * gb.w + bc.w;
  if (BF) {
    unsigned short* op = (unsigned short*)outv + (size_t)row * DIM + lane * 4;
    unsigned short t0[4] = {f2bf(r0), f2bf(r1), f2bf(r2), f2bf(r3)};
    unsigned short t1[4] = {f2bf(r4), f2bf(r5), f2bf(r6), f2bf(r7)};
    *(uint2*)op = *(const uint2*)t0;
    *(uint2*)(op + 256) = *(const uint2*)t1;
  } else {
    float4* op = (float4*)outv + (size_t)row * (DIM / 4) + lane;
    op[0] = make_float4(r0, r1, r2, r3);
    op[64] = make_float4(r4, r5, r6, r7);
  }
}

// ---------------------------------------------------------------------------
// bf16 MFMA GEMM v4 (R7 proven version): DMA staging + XCD-aware 1-D grid
// swizzle, 2-buffer LDS, __syncthreads per K-step (compiler-scheduled).
// R8's counted-vmcnt 3-buffer variant REGRESSED (-20us): cost qkv 1 block/CU
// of occupancy and pinned compiler scheduling. Do not re-attempt without
// per-kernel timing.
// EPI: 1 = bias+res -> fp32; 2 = bias+GELU -> bf16; 3 = bias -> bf16;
//      5 = bias -> fp32 to Cf and Cf2 (embed); 6 = bias+RoPE -> bf16 (WN=64,
//          q scaled by 0.125*log2e for exp2 softmax downstream).
// ---------------------------------------------------------------------------
template <int TM, int TN, int KSTEP, int EPI>
__global__ __launch_bounds__(256) void mfma_gemm(
    const unsigned short* __restrict__ A, const unsigned short* __restrict__ Bt,
    const float* __restrict__ bias, const float* __restrict__ res,
    float* __restrict__ Cf, float* __restrict__ Cf2,
    unsigned short* __restrict__ Cb, const float2* __restrict__ rtab,
    int M, int N, int K) {
  constexpr int WM = TM / 2, WN = TN / 2;
  constexpr int NI = WM / 16, NJ = WN / 16;
  constexpr int RCH = KSTEP / 8;            // 16B chunks per row (4 or 8)
  constexpr int RPU = 64 / RCH;             // rows per 1KB DMA unit (16 or 8)
  constexpr int AU = TM / RPU;              // A units
  constexpr int NU = (TM + TN) / RPU;       // total units
  constexpr int CPW = NU / 4;               // units per wave
  constexpr int SH = (KSTEP == 32) ? 1 : 0; // row swizzle shift
  __shared__ __align__(16) unsigned short As[2][TM][KSTEP];
  __shared__ __align__(16) unsigned short Bs[2][TN][KSTEP];
  // XCD-aware decode (nwg % 8 == 0 guaranteed by launch config)
  const int nwg = gridDim.x;
  const int nx = N / TN;
  const int wg = (blockIdx.x & 7) * (nwg >> 3) + (blockIdx.x >> 3);
  const int bm = (wg / nx) * TM;
  const int bn = (wg % nx) * TN;
  const int tid = threadIdx.x;
  const int lane = tid & 63, wave = tid >> 6;
  const int quad = lane >> 4, l16 = lane & 15;
  const int wm = (wave & 1) * WM;
  const int wn = (wave >> 1) * WN;
  const int lrow = lane / RCH, lc = lane & (RCH - 1);   // DMA src decomp
  const int rsw = (l16 >> SH) & (RCH - 1);              // read swizzle

  float4v acc[NI][NJ];
  #pragma unroll
  for (int i = 0; i < NI; ++i)
    #pragma unroll
    for (int j = 0; j < NJ; ++j)
      acc[i][j] = (float4v){0.f, 0.f, 0.f, 0.f};

  auto stage = [&](int bufI, int kk) {
    #pragma unroll
    for (int it = 0; it < CPW; ++it) {
      int u = wave * CPW + it;
      if (u < AU) {
        int row = u * RPU + lrow;
        int col16 = lc ^ ((row >> SH) & (RCH - 1));
        gload_lds16(A + (size_t)(bm + row) * K + kk + col16 * 8,
                    &As[bufI][u * RPU][0]);
      } else {
        int row = (u - AU) * RPU + lrow;
        int col16 = lc ^ ((row >> SH) & (RCH - 1));
        gload_lds16(Bt + (size_t)(bn + row) * K + kk + col16 * 8,
                    &Bs[bufI][(u - AU) * RPU][0]);
      }
    }
  };

  stage(0, 0);
  int buf = 0;
  for (int k0 = 0; k0 < K; k0 += KSTEP, buf ^= 1) {
    __syncthreads();   // drains own DMA + barrier: tile visible, other buf free
    if (k0 + KSTEP < K) stage(buf ^ 1, k0 + KSTEP);  // flies across MFMA
    #pragma unroll
    for (int t = 0; t < KSTEP / 32; ++t) {
      short8 af[NI], bfr[NJ];
      int rslot = (t * 4 + quad) ^ rsw;
      #pragma unroll
      for (int i = 0; i < NI; ++i)
        af[i] = *(const short8*)&As[buf][wm + i * 16 + l16][rslot * 8];
      #pragma unroll
      for (int j = 0; j < NJ; ++j)
        bfr[j] = *(const short8*)&Bs[buf][wn + j * 16 + l16][rslot * 8];
      __builtin_amdgcn_s_setprio(1);
      #pragma unroll
      for (int i = 0; i < NI; ++i)
        #pragma unroll
        for (int j = 0; j < NJ; ++j)
          acc[i][j] = __builtin_amdgcn_mfma_f32_16x16x32_bf16(
              af[i], bfr[j], acc[i][j], 0, 0, 0);
      __builtin_amdgcn_s_setprio(0);
    }
  }

  if (EPI == 6) {
    const int sec = (bn + wn) >> 9;   // 0=q, 1=k, 2=v (wave-uniform; WN=64)
    #pragma unroll
    for (int i = 0; i < NI; ++i) {
      int gm0 = bm + wm + i * 16 + quad * 4;
      #pragma unroll
      for (int r = 0; r < 4; ++r) {
        int gm = gm0 + r;
        if (gm >= M) continue;
        size_t rowoff = (size_t)gm * N;
        if (sec < 2) {
          int ip = gm; if (ip >= 2046) ip -= 2046; if (ip >= 1023) ip -= 1023;
          // q pre-scaled by log2e so attn can use exp2 directly
          float sc = (sec == 0) ? 0.125f * 1.44269504f : 1.f;
          #pragma unroll
          for (int j = 0; j < NJ / 2; ++j) {
            int gn = bn + wn + j * 16 + l16;
            float v0 = acc[i][j][r] + bias[gn];
            float v1 = acc[i][j + NJ / 2][r] + bias[gn + 32];
            float2 t = rtab[ip * 32 + j * 16 + l16];
            Cb[rowoff + gn]      = f2bf((v0 * t.x - v1 * t.y) * sc);
            Cb[rowoff + gn + 32] = f2bf((v1 * t.x + v0 * t.y) * sc);
          }
        } else {
          #pragma unroll
          for (int j = 0; j < NJ; ++j) {
            int gn = bn + wn + j * 16 + l16;
            Cb[rowoff + gn] = f2bf(acc[i][j][r] + bias[gn]);
          }
        }
      }
    }
    return;
  }

  #pragma unroll
  for (int j = 0; j < NJ; ++j) {
    int gn = bn + wn + j * 16 + l16;
    float bv = bias[gn];
    #pragma unroll
    for (int i = 0; i < NI; ++i) {
      int gm0 = bm + wm + i * 16 + quad * 4;
      #pragma unroll
      for (int r = 0; r < 4; ++r) {
        int gm = gm0 + r;
        if (gm < M) {
          float v = acc[i][j][r] + bv;
          size_t off = (size_t)gm * N + gn;
          if (EPI == 1) {
            Cf[off] = v + res[off];
          } else if (EPI == 2) {
            Cb[off] = f2bf(0.5f * v * (1.f + erff(v * 0.70710678118f)));
          } else if (EPI == 3) {
            Cb[off] = f2bf(v);
          } else {
            Cf[off] = v;
            Cf2[off] = v;
          }
        }
      }
    }
  }
}

// ---------------------------------------------------------------------------
// MFMA flash attention v5.1 (unchanged from R7): in-block split-K, 8 waves,
// exp2 softmax.
// ---------------------------------------------------------------------------
#define APITCH 72

__global__ __launch_bounds__(512, 4) void attn_kernel(
    const unsigned short* __restrict__ qkvb, unsigned short* __restrict__ o) {
  const int bid = blockIdx.x;
  const int xcd = bid & 7, slot = bid >> 3;
  const int qt0 = (slot & 15) * 64;
  const int gh = xcd + 8 * (slot >> 4);    // 0..31
  const int h = gh & 7, b = gh >> 3;

  const int tid = threadIdx.x;
  const int lane = tid & 63, wave = tid >> 6;
  const int quad = lane >> 4, l16 = lane & 15;
  const int half = wave >> 2, wq = wave & 3;

  __shared__ __align__(16) unsigned short Ks[2][64][APITCH];  // [half][key][d]
  __shared__ __align__(16) unsigned short Vt[2][64][APITCH];  // [half][d][key]
  __shared__ __align__(16) unsigned short Ps[8][16][APITCH];  // per-wave P; merge buf

  short8 aq0 = {0, 0, 0, 0, 0, 0, 0, 0}, aq1 = aq0;
  {
    int qrow = qt0 + wq * 16 + l16;
    if (qrow < NPATCH) {
      const uint4* qr = (const uint4*)(qkvb + (size_t)(b * NPATCH + qrow) * (3 * DIM) + h * HD + quad * 8);
      aq0 = __builtin_bit_cast(short8, qr[0]);
      aq1 = __builtin_bit_cast(short8, qr[4]);
    }
  }

  const int krow = tid >> 2, kc0 = (tid & 3) * 16;
  const int kp2 = tid & 63, dg = tid >> 6;
  uint4 pk0, pk1, pv0, pv1;
  auto load_kv = [&](int js) {
    pk0 = pk1 = pv0 = pv1 = make_uint4(0u, 0u, 0u, 0u);
    int jk = js + krow;
    if (jk < NPATCH) {
      const unsigned short* kb = qkvb + (size_t)(b * NPATCH + jk) * (3 * DIM) + DIM + h * HD;
      pk0 = *(const uint4*)(kb + kc0);
      pk1 = *(const uint4*)(kb + kc0 + 8);
    }
    int jv = js + 2 * kp2;
    const unsigned short* vb = qkvb + (size_t)(b * NPATCH + jv) * (3 * DIM) + 2 * DIM + h * HD + dg * 8;
    if (jv < NPATCH)     pv0 = *(const uint4*)vb;
    if (jv + 1 < NPATCH) pv1 = *(const uint4*)(vb + 3 * DIM);
  };

  load_kv(0);

  float4v accO[4];
  #pragma unroll
  for (int j2 = 0; j2 < 4; ++j2) accO[j2] = (float4v){0.f, 0.f, 0.f, 0.f};
  float m_run[4] = {-1e30f, -1e30f, -1e30f, -1e30f};
  float lp[4] = {0.f, 0.f, 0.f, 0.f};

  constexpr int NIT = (NPATCH + 127) / 128;   // 8 slabs of 128 keys
  for (int it = 0; it < NIT; ++it) {
    if (it > 0) __syncthreads();
    {
      *(uint4*)&Ks[krow >> 6][krow & 63][kc0] = pk0;
      *(uint4*)&Ks[krow >> 6][krow & 63][kc0 + 8] = pk1;
      unsigned short va[8], vb8[8];
      *(uint4*)&va[0] = pv0;
      *(uint4*)&vb8[0] = pv1;
      const int vh = kp2 >> 5, lp2 = kp2 & 31;
      #pragma unroll
      for (int u = 0; u < 8; ++u) {
        unsigned pk = (unsigned)va[u] | ((unsigned)vb8[u] << 16);
        *(unsigned*)&Vt[vh][dg * 8 + u][2 * lp2] = pk;
      }
    }
    __syncthreads();
    if (it + 1 < NIT) load_kv((it + 1) * 128);

    const int j0 = it * 128 + half * 64;

    float4v s[4];
    __builtin_amdgcn_s_setprio(1);
    #pragma unroll
    for (int j = 0; j < 4; ++j) {
      s[j] = (float4v){0.f, 0.f, 0.f, 0.f};
      short8 bk0 = *(const short8*)&Ks[half][j * 16 + l16][quad * 8];
      short8 bk1 = *(const short8*)&Ks[half][j * 16 + l16][32 + quad * 8];
      s[j] = __builtin_amdgcn_mfma_f32_16x16x32_bf16(aq0, bk0, s[j], 0, 0, 0);
      s[j] = __builtin_amdgcn_mfma_f32_16x16x32_bf16(aq1, bk1, s[j], 0, 0, 0);
    }
    __builtin_amdgcn_s_setprio(0);

    // online softmax in exp2 units (s already scaled by log2e)
    float mx[4];
    #pragma unroll
    for (int r = 0; r < 4; ++r)
      mx[r] = fmaxf(fmaxf(s[0][r], s[1][r]), fmaxf(s[2][r], s[3][r]));
    #pragma unroll
    for (int mask = 1; mask < 16; mask <<= 1)
      #pragma unroll
      for (int r = 0; r < 4; ++r)
        mx[r] = fmaxf(mx[r], __shfl_xor(mx[r], mask));
    float gmax = fmaxf(fmaxf(mx[0] - m_run[0], mx[1] - m_run[1]),
                       fmaxf(mx[2] - m_run[2], mx[3] - m_run[3]));
    if (!__all(gmax <= 11.0f)) {   // defer-max: 11 bits ~ 7.6 nats
      #pragma unroll
      for (int r = 0; r < 4; ++r) {
        float mnew = fmaxf(m_run[r], mx[r]);
        float al = exp2f(m_run[r] - mnew);
        m_run[r] = mnew;
        lp[r] *= al;
        #pragma unroll
        for (int j2 = 0; j2 < 4; ++j2) accO[j2][r] *= al;
      }
    }
    #pragma unroll
    for (int j = 0; j < 4; ++j) {
      bool valid = (j0 + j * 16 + l16) < NPATCH;
      #pragma unroll
      for (int r = 0; r < 4; ++r) {
        float p = valid ? exp2f(s[j][r] - m_run[r]) : 0.f;
        lp[r] += p;
        Ps[wave][quad * 4 + r][j * 16 + l16] = f2bf(p);
      }
    }

    short8 pa0 = *(const short8*)&Ps[wave][l16][quad * 8];
    short8 pa1 = *(const short8*)&Ps[wave][l16][32 + quad * 8];
    __builtin_amdgcn_s_setprio(1);
    #pragma unroll
    for (int j2 = 0; j2 < 4; ++j2) {
      short8 v0 = *(const short8*)&Vt[half][j2 * 16 + l16][quad * 8];
      short8 v1 = *(const short8*)&Vt[half][j2 * 16 + l16][32 + quad * 8];
      accO[j2] = __builtin_amdgcn_mfma_f32_16x16x32_bf16(pa0, v0, accO[j2], 0, 0, 0);
      accO[j2] = __builtin_amdgcn_mfma_f32_16x16x32_bf16(pa1, v1, accO[j2], 0, 0, 0);
    }
    __builtin_amdgcn_s_setprio(0);
  }

  #pragma unroll
  for (int mask = 1; mask < 16; mask <<= 1)
    #pragma unroll
    for (int r = 0; r < 4; ++r)
      lp[r] += __shfl_xor(lp[r], mask);

  float* Pf = (float*)&Ps[0][0][0];
  __syncthreads();
  if (half == 1) {
    #pragma unroll
    for (int j2 = 0; j2 < 4; ++j2)
      #pragma unroll
      for (int r = 0; r < 4; ++r)
        Pf[((wq * 64 + lane) << 4) + j2 * 4 + r] = accO[j2][r];
    if (l16 == 0) {
      #pragma unroll
      for (int r = 0; r < 4; ++r) {
        Pf[4096 + ((wq * 16 + quad * 4 + r) << 1)]     = m_run[r];
        Pf[4096 + ((wq * 16 + quad * 4 + r) << 1) + 1] = lp[r];
      }
    }
  }
  __syncthreads();
  if (half == 0) {
    #pragma unroll
    for (int r = 0; r < 4; ++r) {
      float m1 = Pf[4096 + ((wq * 16 + quad * 4 + r) << 1)];
      float l1 = Pf[4096 + ((wq * 16 + quad * 4 + r) << 1) + 1];
      float M = fmaxf(m_run[r], m1);
      float w0 = exp2f(m_run[r] - M), w1 = exp2f(m1 - M);
      float inv = 1.f / (w0 * lp[r] + w1 * l1);
      int qi = qt0 + wq * 16 + quad * 4 + r;
      if (qi < NPATCH) {
        size_t off = (size_t)(b * NPATCH + qi) * DIM + h * HD + l16;
        #pragma unroll
        for (int j2 = 0; j2 < 4; ++j2) {
          float a1 = Pf[((wq * 64 + lane) << 4) + j2 * 4 + r];
          o[off + j2 * 16] = f2bf((w0 * accO[j2][r] + w1 * a1) * inv);
        }
      }
    }
  }
}

// ---------------------------------------------------------------------------
extern "C" void kernel_launch(void* const* d_in, const int* in_sizes, int n_in,
                              void* d_out, int out_size, void* d_ws, size_t ws_size,
                              hipStream_t stream) {
  const float* x      = (const float*)d_in[0];
  const float* W_emb  = (const float*)d_in[1];
  const float* b_emb  = (const float*)d_in[2];
  const float* ln1_g  = (const float*)d_in[3];
  const float* ln1_b  = (const float*)d_in[4];
  const float* W_qkv  = (const float*)d_in[5];
  const float* b_qkv  = (const float*)d_in[6];
  const float* W_proj = (const float*)d_in[7];
  const float* b_proj = (const float*)d_in[8];
  const float* ln2_g  = (const float*)d_in[9];
  const float* ln2_b  = (const float*)d_in[10];
  const float* W_mlp1 = (const float*)d_in[11];
  const float* b_mlp1 = (const float*)d_in[12];
  const float* W_mlp2 = (const float*)d_in[13];
  const float* b_mlp2 = (const float*)d_in[14];
  const float* lnf_g  = (const float*)d_in[15];
  const float* lnf_b  = (const float*)d_in[16];
  float* out = (float*)d_out;

  float* h              = (float*)d_ws;
  unsigned short* qkvb  = (unsigned short*)(h + (size_t)M_ROWS * DIM);
  unsigned short* midbf = qkvb;   // alias: qkvb dead after attn
  unsigned short* ybf   = qkvb + (size_t)M_ROWS * MLP_HID;
  unsigned short* obf   = ybf;    // alias: ybf dead after its GEMM
  unsigned short* wqkv_t  = ybf + (size_t)M_ROWS * DIM;
  unsigned short* wproj_t = wqkv_t  + (size_t)NLAYERS * DIM * 3 * DIM;
  unsigned short* wmlp1_t = wproj_t + (size_t)NLAYERS * DIM * DIM;
  unsigned short* wmlp2_t = wmlp1_t + (size_t)NLAYERS * DIM * MLP_HID;
  float2* rtab = (float2*)(wmlp2_t + (size_t)NLAYERS * MLP_HID * DIM);
  unsigned short* Pm    = (unsigned short*)(rtab + (size_t)NPATCH * 32);
  unsigned short* Wembt = Pm + (size_t)M_ROWS * KEMB;

  prep_kernel<<<dim3(PB6), 256, 0, stream>>>(
      W_qkv, wqkv_t, W_proj, wproj_t, W_mlp1, wmlp1_t, W_mlp2, wmlp2_t,
      x, Pm, W_emb, Wembt, rtab);

  const int LNG = (M_ROWS + 3) / 4;        // 1023
  // 1-D swizzled grids: nwg = (N/TN) * ceil(M/TM), all divisible by 8
  const int G64x64  = (DIM / 64) * 64;         // 512
  const int Gqkv    = (3 * DIM / 128) * 64;    // 768
  const int Gmlp1   = (MLP_HID / 128) * 64;    // 1024 (64x128 tiles)

  // embed: out & h = Pm @ Wembt^T + b_emb  (64x64, BK=64)
  mfma_gemm<64, 64, 64, 5><<<dim3(G64x64), 256, 0, stream>>>(
      Pm, Wembt, b_emb, nullptr, out, h, nullptr, nullptr, M_ROWS, DIM, KEMB);

  for (int L = 0; L < NLAYERS; ++L) {
    ln_kernel<true><<<LNG, 256, 0, stream>>>(h, ln1_g + L * DIM, ln1_b + L * DIM, ybf, M_ROWS);
    // qkv with fused RoPE (64x128, BK=64)
    mfma_gemm<64, 128, 64, 6><<<dim3(Gqkv), 256, 0, stream>>>(
        ybf, wqkv_t + (size_t)L * DIM * 3 * DIM, b_qkv + L * 3 * DIM,
        nullptr, nullptr, nullptr, qkvb, rtab, M_ROWS, 3 * DIM, DIM);
    attn_kernel<<<dim3(512), 512, 0, stream>>>(qkvb, obf);
    // proj: h += o @ Wp + bias  (64x64, BK=64)
    mfma_gemm<64, 64, 64, 1><<<dim3(G64x64), 256, 0, stream>>>(
        obf, wproj_t + (size_t)L * DIM * DIM, b_proj + L * DIM,
        h, h, nullptr, nullptr, nullptr, M_ROWS, DIM, DIM);
    ln_kernel<true><<<LNG, 256, 0, stream>>>(h, ln2_g + L * DIM, ln2_b + L * DIM, ybf, M_ROWS);
    // mlp1 + GELU (64x128, BK=64: 1024 blocks, 3 blk/CU LDS-resident)
    mfma_gemm<64, 128, 64, 2><<<dim3(Gmlp1), 256, 0, stream>>>(
        ybf, wmlp1_t + (size_t)L * DIM * MLP_HID, b_mlp1 + L * MLP_HID,
        nullptr, nullptr, nullptr, midbf, nullptr, M_ROWS, MLP_HID, DIM);
    // mlp2: h += mid @ Wm2 + bias  (64x64, BK=64)
    mfma_gemm<64, 64, 64, 1><<<dim3(G64x64), 256, 0, stream>>>(
        midbf, wmlp2_t + (size_t)L * MLP_HID * DIM, b_mlp2 + L * DIM,
        h, h, nullptr, nullptr, nullptr, M_ROWS, DIM, MLP_HID);
  }

  ln_kernel<false><<<LNG, 256, 0, stream>>>(h, lnf_g, lnf_b, out + (size_t)M_ROWS * DIM, M_ROWS);
}